// Round 2
// baseline (61.886 us; speedup 1.0000x reference)
//
#include <hip/hip_runtime.h>

// Problem constants (fixed by the reference file): B=8, N=4096.
#define NN 4096
#define BB 8

// Prologue: convert I = state[:,2,:] (8x4096 f32) to f64 in workspace.
__global__ __launch_bounds__(256) void cvt_I_kernel(const float* __restrict__ state,
                                                    double* __restrict__ I64) {
    const int idx = blockIdx.x * 256 + threadIdx.x;  // 0 .. BB*NN-1
    if (idx < BB * NN) {
        const int b = idx >> 12;          // NN = 4096 = 2^12
        const int k = idx & (NN - 1);
        I64[idx] = (double)state[((size_t)b * 4 + 2) * NN + k];
    }
}

// One block per node j. 256 threads; each lane owns 4 consecutive k per
// iteration (float4 w-load, double2 I64-loads), 4 iterations cover NN.
// prod_b = Prod_k (1 - ISNet[j,k]*S[b,j]*I[b,k]*p01) in f64, then 4x4 mix +
// cumulative-threshold sampling by threads 0..7.
template <bool USE64>
__global__ __launch_bounds__(256) void epi_main(
    const float* __restrict__ state,    // [B,4,N]
    const float* __restrict__ ISNet,    // [N,N]
    const float* __restrict__ psMatrix, // [4,4]
    const float* __restrict__ U,        // [N]
    const double* __restrict__ I64,     // [B,N] pre-converted (if USE64)
    float* __restrict__ out)            // [B,4,N]
{
    const int j   = blockIdx.x;
    const int tid = threadIdx.x;

    const double p01 = (double)psMatrix[1];  // psM[0,1] == psMatrix[0,1]

    double c[BB], prod[BB];
    #pragma unroll
    for (int b = 0; b < BB; ++b) {
        c[b]    = (double)state[(size_t)b * 4 * NN + j] * p01;  // S[b,j]*p01
        prod[b] = 1.0;
    }

    const float4* __restrict__ w4 = (const float4*)(ISNet + (size_t)j * NN);

    #pragma unroll
    for (int it = 0; it < NN / (256 * 4); ++it) {   // 4 iterations
        const int k4 = tid + it * 256;              // group of 4 k's
        const float4 wf = w4[k4];
        const double w0 = (double)wf.x, w1 = (double)wf.y,
                     w2 = (double)wf.z, w3 = (double)wf.w;
        #pragma unroll
        for (int b = 0; b < BB; ++b) {
            double i0, i1, i2, i3;
            if constexpr (USE64) {
                const double2* __restrict__ ip =
                    (const double2*)(I64 + (size_t)b * NN) + 2 * k4;
                const double2 iv0 = ip[0];
                const double2 iv1 = ip[1];
                i0 = iv0.x; i1 = iv0.y; i2 = iv1.x; i3 = iv1.y;
            } else {
                const float4 iv = ((const float4*)(state + ((size_t)b * 4 + 2) * NN))[k4];
                i0 = (double)iv.x; i1 = (double)iv.y; i2 = (double)iv.z; i3 = (double)iv.w;
            }
            const double z0 = c[b] * (w0 * i0);
            const double z1 = c[b] * (w1 * i1);
            const double z2 = c[b] * (w2 * i2);
            const double z3 = c[b] * (w3 * i3);
            // prod *= (1 - z), single rounding per factor
            prod[b] = fma(-z0, prod[b], prod[b]);
            prod[b] = fma(-z1, prod[b], prod[b]);
            prod[b] = fma(-z2, prod[b], prod[b]);
            prod[b] = fma(-z3, prod[b], prod[b]);
        }
    }

    // Multiply-reduce across the 64-lane wave.
    #pragma unroll
    for (int off = 32; off > 0; off >>= 1) {
        #pragma unroll
        for (int b = 0; b < BB; ++b)
            prod[b] *= __shfl_down(prod[b], off, 64);
    }

    // Cross-wave reduce via LDS (4 waves).
    __shared__ double red[4][BB];
    const int wave = tid >> 6, lane = tid & 63;
    if (lane == 0) {
        #pragma unroll
        for (int b = 0; b < BB; ++b) red[wave][b] = prod[b];
    }
    __syncthreads();

    if (tid < BB) {
        const int b = tid;
        const double tot = red[0][b] * red[1][b] * red[2][b] * red[3][b];
        const double ps1 = 1.0 - tot;

        // expand_psMatrix in f64
        double pm[4][4];
        #pragma unroll
        for (int r = 0; r < 4; ++r) {
            double s = 0.0;
            #pragma unroll
            for (int q = 0; q < 4; ++q) {
                pm[r][q] = (double)psMatrix[r * 4 + q];
                s += pm[r][q];
            }
            pm[r][r] += (1.0 - s);
        }

        double st[4];
        #pragma unroll
        for (int r = 0; r < 4; ++r)
            st[r] = (double)state[(size_t)b * 4 * NN + r * NN + j];

        const double S = st[0];
        const double ps10[4] = {1.0 - ps1, ps1, 0.0, 0.0};

        double P[4];
        #pragma unroll
        for (int i = 0; i < 4; ++i) {
            double acc = S * ps10[i];
            #pragma unroll
            for (int r = 1; r < 4; ++r)
                acc += pm[r][i] * st[r];
            P[i] = acc;
        }

        double u = (double)U[j];
        #pragma unroll
        for (int i = 0; i < 4; ++i) {
            u -= P[i];
            const double s = (u < 0.0) ? 1.0 : 0.0;
            out[(size_t)b * 4 * NN + i * NN + j] = (float)s;
            u += s;
        }
    }
}

extern "C" void kernel_launch(void* const* d_in, const int* in_sizes, int n_in,
                              void* d_out, int out_size, void* d_ws, size_t ws_size,
                              hipStream_t stream) {
    const float* state    = (const float*)d_in[0];  // [8,4,4096]
    const float* ISNet    = (const float*)d_in[1];  // [4096,4096]
    const float* psMatrix = (const float*)d_in[2];  // [4,4]
    const float* U        = (const float*)d_in[3];  // [4096]
    float* out            = (float*)d_out;          // [8,4,4096]

    const size_t need = (size_t)BB * NN * sizeof(double);
    if (ws_size >= need) {
        double* I64 = (double*)d_ws;
        cvt_I_kernel<<<(BB * NN) / 256, 256, 0, stream>>>(state, I64);
        epi_main<true><<<NN, 256, 0, stream>>>(state, ISNet, psMatrix, U, I64, out);
    } else {
        epi_main<false><<<NN, 256, 0, stream>>>(state, ISNet, psMatrix, U, nullptr, out);
    }
}

// Round 3
// 33.243 us; speedup vs baseline: 1.8616x; 1.8616x over previous
//
#include <hip/hip_runtime.h>

// Problem constants (fixed by the reference file): B=8, N=4096.
#define NN 4096
#define BB 8

// One block per node j. 256 threads; each lane owns 4 consecutive k per
// iteration (float4 loads), 4 iterations cover NN. Explicit A/B register
// double-buffering keeps 9 loads in flight while computing.
//
// Math: z_bk = (S_bj*p01*w_jk)*I_bk in f32; exact pair-combine in f32:
//   q = z0+z1-z0*z1 = fmaf(-z0,z1,z0+z1)   ((1-z0)(1-z1) = 1-q)
// then the running product stays in f64: prod = fma(-q, prod, prod).
__global__ __launch_bounds__(256) void epi_kernel(
    const float* __restrict__ state,    // [B,4,N]
    const float* __restrict__ ISNet,    // [N,N]
    const float* __restrict__ psMatrix, // [4,4]
    const float* __restrict__ U,        // [N]
    float* __restrict__ out)            // [B,4,N]
{
    const int j   = blockIdx.x;
    const int tid = threadIdx.x;

    const float p01 = psMatrix[1];  // psM[0,1] == psMatrix[0,1]

    float  cf[BB];
    double prod[BB];
    #pragma unroll
    for (int b = 0; b < BB; ++b) {
        cf[b]   = state[(size_t)b * 4 * NN + j] * p01;  // S[b,j]*p01 (f32)
        prod[b] = 1.0;
    }

    const float4* __restrict__ w4 = (const float4*)(ISNet + (size_t)j * NN);

    // I row base pointers (state[b][2][*]), compile-time-indexed.
    const float4* __restrict__ i4_0 = (const float4*)(state + (0 * 4 + 2) * NN);
    const float4* __restrict__ i4_1 = (const float4*)(state + (1 * 4 + 2) * NN);
    const float4* __restrict__ i4_2 = (const float4*)(state + (2 * 4 + 2) * NN);
    const float4* __restrict__ i4_3 = (const float4*)(state + (3 * 4 + 2) * NN);
    const float4* __restrict__ i4_4 = (const float4*)(state + (4 * 4 + 2) * NN);
    const float4* __restrict__ i4_5 = (const float4*)(state + (5 * 4 + 2) * NN);
    const float4* __restrict__ i4_6 = (const float4*)(state + (6 * 4 + 2) * NN);
    const float4* __restrict__ i4_7 = (const float4*)(state + (7 * 4 + 2) * NN);

#define LOAD_SET(wreg, ireg, idx)                                              \
    do {                                                                       \
        const int _x = (idx);                                                  \
        wreg    = w4[_x];                                                      \
        ireg[0] = i4_0[_x]; ireg[1] = i4_1[_x];                                \
        ireg[2] = i4_2[_x]; ireg[3] = i4_3[_x];                                \
        ireg[4] = i4_4[_x]; ireg[5] = i4_5[_x];                                \
        ireg[6] = i4_6[_x]; ireg[7] = i4_7[_x];                                \
    } while (0)

    float4 wA, wB;
    float4 iA[BB], iB[BB];

    auto compute = [&](const float4& wv, const float4 (&iv)[BB]) {
        #pragma unroll
        for (int b = 0; b < BB; ++b) {
            const float z0 = (cf[b] * wv.x) * iv[b].x;
            const float z1 = (cf[b] * wv.y) * iv[b].y;
            const float z2 = (cf[b] * wv.z) * iv[b].z;
            const float z3 = (cf[b] * wv.w) * iv[b].w;
            const float q01 = fmaf(-z0, z1, z0 + z1);  // exact (1-z0)(1-z1)=1-q01
            const float q23 = fmaf(-z2, z3, z2 + z3);
            prod[b] = fma(-(double)q01, prod[b], prod[b]);
            prod[b] = fma(-(double)q23, prod[b], prod[b]);
        }
    };

    // Software pipeline: 4 iterations over the row, prefetch next before compute.
    LOAD_SET(wA, iA, tid);
    LOAD_SET(wB, iB, tid + 256);
    compute(wA, iA);
    LOAD_SET(wA, iA, tid + 512);
    compute(wB, iB);
    LOAD_SET(wB, iB, tid + 768);
    compute(wA, iA);
    compute(wB, iB);
#undef LOAD_SET

    // Multiply-reduce across the 64-lane wave.
    #pragma unroll
    for (int off = 32; off > 0; off >>= 1) {
        #pragma unroll
        for (int b = 0; b < BB; ++b)
            prod[b] *= __shfl_down(prod[b], off, 64);
    }

    // Cross-wave reduce via LDS (4 waves).
    __shared__ double red[4][BB];
    const int wave = tid >> 6, lane = tid & 63;
    if (lane == 0) {
        #pragma unroll
        for (int b = 0; b < BB; ++b) red[wave][b] = prod[b];
    }
    __syncthreads();

    if (tid < BB) {
        const int b = tid;
        const double tot = red[0][b] * red[1][b] * red[2][b] * red[3][b];
        const double ps1 = 1.0 - tot;

        // expand_psMatrix in f64
        double pm[4][4];
        #pragma unroll
        for (int r = 0; r < 4; ++r) {
            double s = 0.0;
            #pragma unroll
            for (int q = 0; q < 4; ++q) {
                pm[r][q] = (double)psMatrix[r * 4 + q];
                s += pm[r][q];
            }
            pm[r][r] += (1.0 - s);
        }

        double st[4];
        #pragma unroll
        for (int r = 0; r < 4; ++r)
            st[r] = (double)state[(size_t)b * 4 * NN + r * NN + j];

        const double S = st[0];
        const double ps10[4] = {1.0 - ps1, ps1, 0.0, 0.0};

        double P[4];
        #pragma unroll
        for (int i = 0; i < 4; ++i) {
            double acc = S * ps10[i];
            #pragma unroll
            for (int r = 1; r < 4; ++r)
                acc += pm[r][i] * st[r];
            P[i] = acc;
        }

        double u = (double)U[j];
        #pragma unroll
        for (int i = 0; i < 4; ++i) {
            u -= P[i];
            const double s = (u < 0.0) ? 1.0 : 0.0;
            out[(size_t)b * 4 * NN + i * NN + j] = (float)s;
            u += s;
        }
    }
}

extern "C" void kernel_launch(void* const* d_in, const int* in_sizes, int n_in,
                              void* d_out, int out_size, void* d_ws, size_t ws_size,
                              hipStream_t stream) {
    const float* state    = (const float*)d_in[0];  // [8,4,4096]
    const float* ISNet    = (const float*)d_in[1];  // [4096,4096]
    const float* psMatrix = (const float*)d_in[2];  // [4,4]
    const float* U        = (const float*)d_in[3];  // [4096]
    float* out            = (float*)d_out;          // [8,4,4096]

    epi_kernel<<<NN, 256, 0, stream>>>(state, ISNet, psMatrix, U, out);
}

// Round 4
// 24.182 us; speedup vs baseline: 2.5591x; 1.3747x over previous
//
#include <hip/hip_runtime.h>

// Problem constants (fixed by the reference file): B=8, N=4096.
#define NN 4096
#define BB 8
#define JT 4   // ISNet rows (j) per block

// Grid: NN/JT = 1024 blocks x 256 threads (4 waves).
// Block owns rows j0..j0+3. Wave w owns batches {2w, 2w+1} over ALL k.
// Lane l covers float4-groups x = it*64 + l, it = 0..15 (interleaved, coalesced).
// Per factor: z = (S*p01*w)*I in f32; 4 factors combine exactly-in-f32 to one q
// (pairwise fmaf), then the running product stays f64: prod = fma(-q, prod, prod).
// Each wave's (j,b) pairs are disjoint -> 6-level butterfly on 8 f64, no
// cross-wave combine.

__device__ __forceinline__ float2 pk_mul(float2 a, float2 b) {
    return make_float2(a.x * b.x, a.y * b.y);
}
__device__ __forceinline__ float2 pk_add(float2 a, float2 b) {
    return make_float2(a.x + b.x, a.y + b.y);
}
__device__ __forceinline__ float2 pk_fnma(float2 a, float2 b, float2 c) {  // c - a*b
    return make_float2(fmaf(-a.x, b.x, c.x), fmaf(-a.y, b.y, c.y));
}

__global__ __launch_bounds__(256) void epi_kernel(
    const float* __restrict__ state,    // [B,4,N]
    const float* __restrict__ ISNet,    // [N,N]
    const float* __restrict__ psMatrix, // [4,4]
    const float* __restrict__ U,        // [N]
    float* __restrict__ out)            // [B,4,N]
{
    const int j0   = blockIdx.x * JT;
    const int tid  = threadIdx.x;
    const int wave = tid >> 6;
    const int lane = tid & 63;
    const int b0   = wave * 2;          // this wave's two batches

    const float p01 = psMatrix[1];      // psM[0,1] == psMatrix[0,1]

    float  cf[JT][2];
    double prod[JT][2];
    #pragma unroll
    for (int jj = 0; jj < JT; ++jj) {
        #pragma unroll
        for (int bi = 0; bi < 2; ++bi) {
            cf[jj][bi]   = state[(size_t)(b0 + bi) * 4 * NN + (j0 + jj)] * p01;
            prod[jj][bi] = 1.0;
        }
    }

    const float4* __restrict__ w0 = (const float4*)(ISNet + (size_t)(j0 + 0) * NN);
    const float4* __restrict__ w1 = (const float4*)(ISNet + (size_t)(j0 + 1) * NN);
    const float4* __restrict__ w2 = (const float4*)(ISNet + (size_t)(j0 + 2) * NN);
    const float4* __restrict__ w3 = (const float4*)(ISNet + (size_t)(j0 + 3) * NN);
    const float4* __restrict__ i0 = (const float4*)(state + ((size_t)(b0 + 0) * 4 + 2) * NN);
    const float4* __restrict__ i1 = (const float4*)(state + ((size_t)(b0 + 1) * 4 + 2) * NN);

    float4 wA[JT], wB[JT], iA[2], iB[2];

#define LOADSET(W, I, X)                                   \
    do {                                                   \
        const int _x = (X);                                \
        W[0] = w0[_x]; W[1] = w1[_x];                      \
        W[2] = w2[_x]; W[3] = w3[_x];                      \
        I[0] = i0[_x]; I[1] = i1[_x];                      \
    } while (0)

    auto compute = [&](const float4 (&W)[JT], const float4 (&I)[2]) {
        #pragma unroll
        for (int jj = 0; jj < JT; ++jj) {
            const float2 w01 = make_float2(W[jj].x, W[jj].y);
            const float2 w23 = make_float2(W[jj].z, W[jj].w);
            #pragma unroll
            for (int bi = 0; bi < 2; ++bi) {
                const float2 c2  = make_float2(cf[jj][bi], cf[jj][bi]);
                const float2 i01 = make_float2(I[bi].x, I[bi].y);
                const float2 i23 = make_float2(I[bi].z, I[bi].w);
                const float2 z01 = pk_mul(pk_mul(c2, w01), i01);
                const float2 z23 = pk_mul(pk_mul(c2, w23), i23);
                // (1-z0)(1-z2) = 1-qa, (1-z1)(1-z3) = 1-qb  (packed pairwise)
                const float2 q2 = pk_fnma(z01, z23, pk_add(z01, z23));
                // (1-qa)(1-qb) = 1-q
                const float q = fmaf(-q2.x, q2.y, q2.x + q2.y);
                prod[jj][bi] = fma(-(double)q, prod[jj][bi], prod[jj][bi]);
            }
        }
    };

    // Software pipeline over 16 k-group iterations, A/B register buffers.
    LOADSET(wA, iA, lane);
    LOADSET(wB, iB, lane + 64);
    #pragma unroll
    for (int it = 0; it < 16; it += 2) {
        compute(wA, iA);
        if (it + 2 < 16) LOADSET(wA, iA, lane + (it + 2) * 64);
        compute(wB, iB);
        if (it + 3 < 16) LOADSET(wB, iB, lane + (it + 3) * 64);
    }
#undef LOADSET

    // Multiply-reduce each wave's 8 disjoint (j,b) products across 64 lanes.
    #pragma unroll
    for (int off = 32; off > 0; off >>= 1) {
        #pragma unroll
        for (int jj = 0; jj < JT; ++jj) {
            #pragma unroll
            for (int bi = 0; bi < 2; ++bi)
                prod[jj][bi] *= __shfl_down(prod[jj][bi], off, 64);
        }
    }

    __shared__ double red[JT][BB];
    if (lane == 0) {
        #pragma unroll
        for (int jj = 0; jj < JT; ++jj) {
            #pragma unroll
            for (int bi = 0; bi < 2; ++bi)
                red[jj][b0 + bi] = prod[jj][bi];
        }
    }
    __syncthreads();

    if (tid < JT * BB) {   // 32 threads: (jj, b)
        const int jj = tid >> 3, b = tid & 7;
        const int j  = j0 + jj;
        const double tot = red[jj][b];
        const double ps1 = 1.0 - tot;

        // expand_psMatrix in f64
        double pm[4][4];
        #pragma unroll
        for (int r = 0; r < 4; ++r) {
            double s = 0.0;
            #pragma unroll
            for (int q = 0; q < 4; ++q) {
                pm[r][q] = (double)psMatrix[r * 4 + q];
                s += pm[r][q];
            }
            pm[r][r] += (1.0 - s);
        }

        double st[4];
        #pragma unroll
        for (int r = 0; r < 4; ++r)
            st[r] = (double)state[(size_t)b * 4 * NN + r * NN + j];

        const double S = st[0];
        const double ps10[4] = {1.0 - ps1, ps1, 0.0, 0.0};

        double P[4];
        #pragma unroll
        for (int i = 0; i < 4; ++i) {
            double acc = S * ps10[i];
            #pragma unroll
            for (int r = 1; r < 4; ++r)
                acc += pm[r][i] * st[r];
            P[i] = acc;
        }

        double u = (double)U[j];
        #pragma unroll
        for (int i = 0; i < 4; ++i) {
            u -= P[i];
            const double s = (u < 0.0) ? 1.0 : 0.0;
            out[(size_t)b * 4 * NN + i * NN + j] = (float)s;
            u += s;
        }
    }
}

extern "C" void kernel_launch(void* const* d_in, const int* in_sizes, int n_in,
                              void* d_out, int out_size, void* d_ws, size_t ws_size,
                              hipStream_t stream) {
    const float* state    = (const float*)d_in[0];  // [8,4,4096]
    const float* ISNet    = (const float*)d_in[1];  // [4096,4096]
    const float* psMatrix = (const float*)d_in[2];  // [4,4]
    const float* U        = (const float*)d_in[3];  // [4096]
    float* out            = (float*)d_out;          // [8,4,4096]

    epi_kernel<<<NN / JT, 256, 0, stream>>>(state, ISNet, psMatrix, U, out);
}

// Round 6
// 23.976 us; speedup vs baseline: 2.5811x; 1.0086x over previous
//
#include <hip/hip_runtime.h>

// Problem constants (fixed by the reference file): B=8, N=4096.
#define NN 4096
#define BB 8
#define JT 4   // ISNet rows (j) per block

// Grid: NN/JT = 1024 blocks x 256 threads (4 waves).
// Block owns rows j0..j0+3. Wave w owns batches {2w, 2w+1} over ALL k.
// 16 pipeline stages of 1 float4 per row; w triple-buffered (prefetch dist 3,
// covers L3 latency), I double-buffered (L2-resident).
// Math (identical to the round-4 pass): z = (S*p01*w)*I in f32, 4 factors
// combine exactly-in-f32 (pairwise fmaf) to one q, running product in f64.
// Reduction: 3 XOR-butterfly levels (every lane holds its mod-8 residue
// partial), select pair g per 8-lane group, 3 down-levels -> lane 8g has the
// full product for pair g.  (Round-5 bug: shfl_down for the first 3 levels
// leaves lanes 8..63 invalid.)

__device__ __forceinline__ float2 pk_mul(float2 a, float2 b) {
    return make_float2(a.x * b.x, a.y * b.y);
}
__device__ __forceinline__ float2 pk_add(float2 a, float2 b) {
    return make_float2(a.x + b.x, a.y + b.y);
}
__device__ __forceinline__ float2 pk_fnma(float2 a, float2 b, float2 c) {  // c - a*b
    return make_float2(fmaf(-a.x, b.x, c.x), fmaf(-a.y, b.y, c.y));
}

__global__ __launch_bounds__(256, 4) void epi_kernel(
    const float* __restrict__ state,    // [B,4,N]
    const float* __restrict__ ISNet,    // [N,N]
    const float* __restrict__ psMatrix, // [4,4]
    const float* __restrict__ U,        // [N]
    float* __restrict__ out)            // [B,4,N]
{
    const int j0   = blockIdx.x * JT;
    const int tid  = threadIdx.x;
    const int wave = tid >> 6;
    const int lane = tid & 63;
    const int b0   = wave * 2;          // this wave's two batches

    const float p01 = psMatrix[1];      // psM[0,1] == psMatrix[0,1]

    float  cf[JT][2];
    double prod[JT][2];
    #pragma unroll
    for (int jj = 0; jj < JT; ++jj) {
        #pragma unroll
        for (int bi = 0; bi < 2; ++bi) {
            cf[jj][bi]   = state[(size_t)(b0 + bi) * 4 * NN + (j0 + jj)] * p01;
            prod[jj][bi] = 1.0;
        }
    }

    const float4* __restrict__ w0 = (const float4*)(ISNet + (size_t)(j0 + 0) * NN);
    const float4* __restrict__ w1 = (const float4*)(ISNet + (size_t)(j0 + 1) * NN);
    const float4* __restrict__ w2 = (const float4*)(ISNet + (size_t)(j0 + 2) * NN);
    const float4* __restrict__ w3 = (const float4*)(ISNet + (size_t)(j0 + 3) * NN);
    const float4* __restrict__ i0 = (const float4*)(state + ((size_t)(b0 + 0) * 4 + 2) * NN);
    const float4* __restrict__ i1 = (const float4*)(state + ((size_t)(b0 + 1) * 4 + 2) * NN);

    float4 wA[JT], wB[JT], wC[JT], ia[2], ib[2];

#define LW(BUF, IDX)                                        \
    do {                                                    \
        const int _x = lane + (IDX) * 64;                   \
        BUF[0] = w0[_x]; BUF[1] = w1[_x];                   \
        BUF[2] = w2[_x]; BUF[3] = w3[_x];                   \
    } while (0)
#define LI(BUF, IDX)                                        \
    do {                                                    \
        const int _x = lane + (IDX) * 64;                   \
        BUF[0] = i0[_x]; BUF[1] = i1[_x];                   \
    } while (0)

    auto compute = [&](const float4 (&W)[JT], const float4 (&I)[2]) {
        #pragma unroll
        for (int jj = 0; jj < JT; ++jj) {
            const float2 w01 = make_float2(W[jj].x, W[jj].y);
            const float2 w23 = make_float2(W[jj].z, W[jj].w);
            #pragma unroll
            for (int bi = 0; bi < 2; ++bi) {
                const float2 c2  = make_float2(cf[jj][bi], cf[jj][bi]);
                const float2 i01 = make_float2(I[bi].x, I[bi].y);
                const float2 i23 = make_float2(I[bi].z, I[bi].w);
                const float2 z01 = pk_mul(pk_mul(c2, w01), i01);
                const float2 z23 = pk_mul(pk_mul(c2, w23), i23);
                const float2 q2  = pk_fnma(z01, z23, pk_add(z01, z23));
                const float  q   = fmaf(-q2.x, q2.y, q2.x + q2.y);
                prod[jj][bi] = fma(-(double)q, prod[jj][bi], prod[jj][bi]);
            }
        }
    };

    // compute stage K, then refill: w buffer for K+3, I buffer for K+2.
#define STEP(W, I, K)                                       \
    do {                                                    \
        compute(W, I);                                      \
        if ((K) + 3 < 16) LW(W, (K) + 3);                   \
        if ((K) + 2 < 16) LI(I, (K) + 2);                   \
    } while (0)

    LW(wA, 0); LI(ia, 0); LW(wB, 1); LI(ib, 1); LW(wC, 2);

    STEP(wA, ia, 0);  STEP(wB, ib, 1);  STEP(wC, ia, 2);  STEP(wA, ib, 3);
    STEP(wB, ia, 4);  STEP(wC, ib, 5);  STEP(wA, ia, 6);  STEP(wB, ib, 7);
    STEP(wC, ia, 8);  STEP(wA, ib, 9);  STEP(wB, ia, 10); STEP(wC, ib, 11);
    STEP(wA, ia, 12); STEP(wB, ib, 13); STEP(wC, ia, 14); STEP(wA, ib, 15);
#undef STEP
#undef LW
#undef LI

    // 3 XOR-butterfly levels: every lane holds the partial product over its
    // residue class {m : m ≡ lane (mod 8)}.
    #pragma unroll
    for (int off = 32; off >= 8; off >>= 1) {
        #pragma unroll
        for (int jj = 0; jj < JT; ++jj) {
            #pragma unroll
            for (int bi = 0; bi < 2; ++bi)
                prod[jj][bi] *= __shfl_xor(prod[jj][bi], off, 64);
        }
    }

    // 8-lane group g reduces pair g: its lanes cover all 8 residues.
    const int g = lane >> 3;
    double v = prod[0][0];
    v = (g == 1) ? prod[0][1] : v;
    v = (g == 2) ? prod[1][0] : v;
    v = (g == 3) ? prod[1][1] : v;
    v = (g == 4) ? prod[2][0] : v;
    v = (g == 5) ? prod[2][1] : v;
    v = (g == 6) ? prod[3][0] : v;
    v = (g == 7) ? prod[3][1] : v;
    v *= __shfl_down(v, 4, 64);
    v *= __shfl_down(v, 2, 64);
    v *= __shfl_down(v, 1, 64);

    __shared__ double red[JT][BB];
    if ((lane & 7) == 0)               // pair g = (jj<<1)|bi
        red[g >> 1][b0 + (g & 1)] = v;
    __syncthreads();

    if (tid < JT * BB) {   // 32 threads: (jj, b)
        const int jj = tid >> 3, b = tid & 7;
        const int j  = j0 + jj;
        const double tot = red[jj][b];
        const double ps1 = 1.0 - tot;

        // expand_psMatrix in f64
        double pm[4][4];
        #pragma unroll
        for (int r = 0; r < 4; ++r) {
            double s = 0.0;
            #pragma unroll
            for (int q = 0; q < 4; ++q) {
                pm[r][q] = (double)psMatrix[r * 4 + q];
                s += pm[r][q];
            }
            pm[r][r] += (1.0 - s);
        }

        double st[4];
        #pragma unroll
        for (int r = 0; r < 4; ++r)
            st[r] = (double)state[(size_t)b * 4 * NN + r * NN + j];

        const double S = st[0];
        const double ps10[4] = {1.0 - ps1, ps1, 0.0, 0.0};

        double P[4];
        #pragma unroll
        for (int i = 0; i < 4; ++i) {
            double acc = S * ps10[i];
            #pragma unroll
            for (int r = 1; r < 4; ++r)
                acc += pm[r][i] * st[r];
            P[i] = acc;
        }

        double u = (double)U[j];
        #pragma unroll
        for (int i = 0; i < 4; ++i) {
            u -= P[i];
            const double s = (u < 0.0) ? 1.0 : 0.0;
            out[(size_t)b * 4 * NN + i * NN + j] = (float)s;
            u += s;
        }
    }
}

extern "C" void kernel_launch(void* const* d_in, const int* in_sizes, int n_in,
                              void* d_out, int out_size, void* d_ws, size_t ws_size,
                              hipStream_t stream) {
    const float* state    = (const float*)d_in[0];  // [8,4,4096]
    const float* ISNet    = (const float*)d_in[1];  // [4096,4096]
    const float* psMatrix = (const float*)d_in[2];  // [4,4]
    const float* U        = (const float*)d_in[3];  // [4096]
    float* out            = (float*)d_out;          // [8,4,4096]

    epi_kernel<<<NN / JT, 256, 0, stream>>>(state, ISNet, psMatrix, U, out);
}